// Round 12
// baseline (271.720 us; speedup 1.0000x reference)
//
#include <hip/hip_runtime.h>

#define N_NODES 20000
#define MP      20096   // N_NODES padded to multiple of 128
#define N_EDGES 320000
#define DIM     512
#define SCAN_BLOCKS 79    // ceil(20224/256)
#define FILL_BLOCKS 1250  // N_EDGES/256
#define W_BLOCKS    512   // 16x16 tiles x 2 weights
#define SORT_BLOCKS 79
#define NBIN 4096         // 256 degree bins x 16 sub-bins (shortens atomic chains)
#define MAXP_BLOCKS 256
#define MAXP_ROWS   79    // ceil(20000/256)

typedef _Float16 half8 __attribute__((ext_vector_type(8)));
typedef float floatx4 __attribute__((ext_vector_type(4)));

#define GLD16(g, l) __builtin_amdgcn_global_load_lds( \
    (const __attribute__((address_space(1))) unsigned int*)(g), \
    (__attribute__((address_space(3))) unsigned int*)(l), 16, 0, 0)

// store helpers: 8 consecutive features from fp32 regs
__device__ inline void store8(_Float16* p, const float* v) {
    half8 o;
#pragma unroll
    for (int i = 0; i < 8; ++i) o[i] = (_Float16)v[i];
    *(half8*)p = o;
}
__device__ inline void store8(float* p, const float* v) {
    *(float4*)&p[0] = make_float4(v[0], v[1], v[2], v[3]);
    *(float4*)&p[4] = make_float4(v[4], v[5], v[6], v[7]);
}

__global__ void k_count(const int* __restrict__ dst, int* __restrict__ cnt) {
    int e = blockIdx.x * blockDim.x + threadIdx.x;
    if (e < N_EDGES) atomicAdd(&cnt[dst[e]], 1);
}

// ---------------------------------------------------------------- parallel scan
__global__ __launch_bounds__(256) void k_scan_a(const int* __restrict__ cnt,
                                                int* __restrict__ bsum) {
    __shared__ int buf[256];
    int gi = blockIdx.x * 256 + threadIdx.x;
    buf[threadIdx.x] = (gi < N_NODES) ? cnt[gi] : 0;
    __syncthreads();
    for (int off = 128; off > 0; off >>= 1) {
        if (threadIdx.x < off) buf[threadIdx.x] += buf[threadIdx.x + off];
        __syncthreads();
    }
    if (threadIdx.x == 0) bsum[blockIdx.x] = buf[0];
}

__global__ __launch_bounds__(128) void k_scan_b(const int* __restrict__ bsum,
                                                int* __restrict__ bbase) {
    __shared__ int buf[128];
    int tid = threadIdx.x;
    int v = (tid < SCAN_BLOCKS) ? bsum[tid] : 0;
    buf[tid] = v;
    __syncthreads();
    for (int off = 1; off < 128; off <<= 1) {
        int t = (tid >= off) ? buf[tid - off] : 0;
        __syncthreads();
        buf[tid] += t;
        __syncthreads();
    }
    if (tid < SCAN_BLOCKS) bbase[tid] = buf[tid] - v;  // exclusive
}

// offs/cursor/dinv + sub-binned degree histogram (for the counting sort)
__global__ __launch_bounds__(256) void k_scan_c(const int* __restrict__ cnt,
                                                const int* __restrict__ bbase,
                                                int* __restrict__ offs,
                                                int* __restrict__ cursor,
                                                float* __restrict__ dinv,
                                                int* __restrict__ hist) {
    __shared__ int buf[256];
    __shared__ int lh[NBIN];
    int tid = threadIdx.x;
#pragma unroll
    for (int k = 0; k < NBIN / 256; ++k) lh[tid + k * 256] = 0;
    int gi = blockIdx.x * 256 + tid;
    int v = (gi < N_NODES) ? cnt[gi] : 0;
    buf[tid] = v;
    __syncthreads();
    for (int off = 1; off < 256; off <<= 1) {
        int t = (tid >= off) ? buf[tid - off] : 0;
        __syncthreads();
        buf[tid] += t;
        __syncthreads();
    }
    int base = bbase[blockIdx.x];
    if (gi < N_NODES) {
        int incl = base + buf[tid];
        offs[gi + 1] = incl;
        cursor[gi] = incl - v;
        dinv[gi] = rsqrtf((float)v + 1.0f);  // +1 self-loop
        if (gi == 0) offs[0] = 0;
        int bin = (v > 255 ? 255 : v) * 16 + (gi & 15);
        atomicAdd(&lh[bin], 1);
    } else if (gi < MP) {
        dinv[gi] = 0.f;  // pad rows: zero (poison-proofs GEMM epilogue)
    }
    __syncthreads();
#pragma unroll
    for (int k = 0; k < NBIN / 256; ++k) {
        int b2 = tid + k * 256;
        if (lh[b2]) atomicAdd(&hist[b2], lh[b2]);
    }
}

// ---------------------------------------------------------------- fused prep
// [0,1250): CSR fill; [1250,1762): W transpose; [1762,1841): counting-sort
// scatter (single-level atomic form, 16 sub-bins). Sort order is a perf
// heuristic only — correctness never depends on it.
__global__ __launch_bounds__(256) void k_prep(const int* __restrict__ src,
                                              const int* __restrict__ dst,
                                              int* __restrict__ cursor,
                                              int* __restrict__ csr_src,
                                              const float* __restrict__ W1,
                                              const float* __restrict__ W2,
                                              _Float16* __restrict__ Wt1,
                                              _Float16* __restrict__ Wt2,
                                              const int* __restrict__ cnt,
                                              const int* __restrict__ hist,
                                              int* __restrict__ bincur,
                                              int* __restrict__ sorted) {
    int b = blockIdx.x;
    if (b < FILL_BLOCKS) {
        int e = b * 256 + threadIdx.x;
        int d = dst[e];
        int pos = atomicAdd(&cursor[d], 1);
        csr_src[pos] = src[e];
        return;
    }
    if (b < FILL_BLOCKS + W_BLOCKS) {
        // W transpose: fp32 [k][n] -> f16 [n][k]
        int local = b - FILL_BLOCKS;
        int z = local >> 8, t = local & 255;
        const float* W = z ? W2 : W1;
        _Float16* Wt = z ? Wt2 : Wt1;
        __shared__ float tile[32][33];
        int bx = (t & 15) * 32, by = (t >> 4) * 32;
        int x = threadIdx.x & 31, y4 = (threadIdx.x >> 5) * 4;
#pragma unroll
        for (int r = 0; r < 4; ++r)
            tile[y4 + r][x] = W[(size_t)(by + y4 + r) * DIM + bx + x];
        __syncthreads();
#pragma unroll
        for (int r = 0; r < 4; ++r)
            Wt[(size_t)(bx + y4 + r) * DIM + by + x] = (_Float16)tile[x][y4 + r];
        return;
    }
    // --- counting-sort scatter (single-level, R10-proven)
    int sb = b - (FILL_BLOCKS + W_BLOCKS);
    __shared__ int sc[NBIN];  // global exclusive base per bin
    __shared__ int ps[256];
    int tid = threadIdx.x;
    int tsum = 0;
#pragma unroll
    for (int k = 0; k < NBIN / 256; ++k) {
        int h = hist[tid * (NBIN / 256) + k];
        sc[tid * (NBIN / 256) + k] = tsum;  // exclusive within this thread's group
        tsum += h;
    }
    ps[tid] = tsum;
    __syncthreads();
    for (int off = 1; off < 256; off <<= 1) {
        int t = (tid >= off) ? ps[tid - off] : 0;
        __syncthreads();
        ps[tid] += t;
        __syncthreads();
    }
    int gbase = ps[tid] - tsum;  // exclusive prefix of this thread's bin group
#pragma unroll
    for (int k = 0; k < NBIN / 256; ++k) sc[tid * (NBIN / 256) + k] += gbase;
    __syncthreads();
    int gi = sb * 256 + tid;
    if (gi < N_NODES) {
        int d = cnt[gi];
        int bin = (d > 255 ? 255 : d) * 16 + (gi & 15);
        int pos = sc[bin] + atomicAdd(&bincur[bin], 1);
        sorted[pos] = gi;
    } else if (gi < MP) {
        sorted[gi] = gi;  // pad ids land at [N_NODES, MP)
    }
}

// ---------------------------------------------------------------- MFMA GEMM (f16 A)
// g[MP,512] f16 = dinv[row] * (A[MP,512] f16 @ Bt[n][k] f16)
__global__ __launch_bounds__(256) void k_gemm_f16(const _Float16* __restrict__ A,
                                                  const _Float16* __restrict__ Bt,
                                                  const float* __restrict__ dinv,
                                                  _Float16* __restrict__ G) {
    __shared__ _Float16 As[128 * 32];  // [m][k], k contiguous
    __shared__ _Float16 Bs[128 * 32];  // [n][k], k contiguous

    int t = threadIdx.x;
    int w = t >> 6, lane = t & 63;
    int lm = lane & 15, quad = lane >> 4;
    int m0 = blockIdx.x * 128, n0 = blockIdx.y * 128;
    int wm = (w & 1) * 64, wn = (w >> 1) * 64;

    floatx4 acc[4][4];
#pragma unroll
    for (int i = 0; i < 4; ++i)
#pragma unroll
        for (int j = 0; j < 4; ++j) acc[i][j] = (floatx4){0.f, 0.f, 0.f, 0.f};

    for (int k0 = 0; k0 < DIM; k0 += 32) {
        __syncthreads();
#pragma unroll
        for (int i = 0; i < 2; ++i) {
            int s = i * 256 + t;
            int m = s >> 2, kk = (s & 3) * 8;
            GLD16(A + (size_t)(m0 + m) * DIM + k0 + kk, As + s * 8);
            GLD16(Bt + (size_t)(n0 + m) * DIM + k0 + kk, Bs + s * 8);
        }
        __syncthreads();

        half8 af[4], bf[4];
#pragma unroll
        for (int i = 0; i < 4; ++i)
            af[i] = *(const half8*)&As[(wm + i * 16 + lm) * 32 + quad * 8];
#pragma unroll
        for (int j = 0; j < 4; ++j)
            bf[j] = *(const half8*)&Bs[(wn + j * 16 + lm) * 32 + quad * 8];
#pragma unroll
        for (int i = 0; i < 4; ++i)
#pragma unroll
            for (int j = 0; j < 4; ++j)
                acc[i][j] = __builtin_amdgcn_mfma_f32_16x16x32_f16(af[i], bf[j], acc[i][j], 0, 0, 0);
    }

#pragma unroll
    for (int i = 0; i < 4; ++i)
#pragma unroll
        for (int r = 0; r < 4; ++r) {
            int row = m0 + wm + i * 16 + quad * 4 + r;
            float dd = dinv[row];  // 0 on pad rows
#pragma unroll
            for (int j = 0; j < 4; ++j) {
                int col = n0 + wn + j * 16 + lm;
                G[(size_t)row * DIM + col] = (_Float16)(dd * acc[i][j][r]);
            }
        }
}

// ---------------------------------------------------------------- MFMA GEMM (fp32 A)
// Layer 1: reads features fp32 directly, converts to f16 during LDS staging.
// B keeps the global_load_lds fast path. Rows >= N_NODES staged as zero
// (features has exactly N_NODES rows — no OOB reads).
__global__ __launch_bounds__(256) void k_gemm_f32A(const float* __restrict__ A,
                                                   const _Float16* __restrict__ Bt,
                                                   const float* __restrict__ dinv,
                                                   _Float16* __restrict__ G) {
    __shared__ _Float16 As[128 * 32];  // [m][k], k contiguous
    __shared__ _Float16 Bs[128 * 32];  // [n][k], k contiguous

    int t = threadIdx.x;
    int w = t >> 6, lane = t & 63;
    int lm = lane & 15, quad = lane >> 4;
    int m0 = blockIdx.x * 128, n0 = blockIdx.y * 128;
    int wm = (w & 1) * 64, wn = (w >> 1) * 64;

    floatx4 acc[4][4];
#pragma unroll
    for (int i = 0; i < 4; ++i)
#pragma unroll
        for (int j = 0; j < 4; ++j) acc[i][j] = (floatx4){0.f, 0.f, 0.f, 0.f};

    for (int k0 = 0; k0 < DIM; k0 += 32) {
        __syncthreads();
#pragma unroll
        for (int i = 0; i < 2; ++i) {  // B: async direct-to-LDS
            int s = i * 256 + t;
            int m = s >> 2, kk = (s & 3) * 8;
            GLD16(Bt + (size_t)(n0 + m) * DIM + k0 + kk, Bs + s * 8);
        }
#pragma unroll
        for (int i = 0; i < 2; ++i) {  // A: fp32 load -> f16 cvt -> LDS
            int s = i * 256 + t;
            int m = s >> 2, kk = (s & 3) * 8;
            int arow = m0 + m;
            half8 h;
            if (arow < N_NODES) {
                float4 a0 = *(const float4*)&A[(size_t)arow * DIM + k0 + kk];
                float4 a1 = *(const float4*)&A[(size_t)arow * DIM + k0 + kk + 4];
                h[0] = (_Float16)a0.x; h[1] = (_Float16)a0.y;
                h[2] = (_Float16)a0.z; h[3] = (_Float16)a0.w;
                h[4] = (_Float16)a1.x; h[5] = (_Float16)a1.y;
                h[6] = (_Float16)a1.z; h[7] = (_Float16)a1.w;
            } else {
#pragma unroll
                for (int q = 0; q < 8; ++q) h[q] = (_Float16)0.f;
            }
            *(half8*)&As[s * 8] = h;
        }
        __syncthreads();

        half8 af[4], bf[4];
#pragma unroll
        for (int i = 0; i < 4; ++i)
            af[i] = *(const half8*)&As[(wm + i * 16 + lm) * 32 + quad * 8];
#pragma unroll
        for (int j = 0; j < 4; ++j)
            bf[j] = *(const half8*)&Bs[(wn + j * 16 + lm) * 32 + quad * 8];
#pragma unroll
        for (int i = 0; i < 4; ++i)
#pragma unroll
            for (int j = 0; j < 4; ++j)
                acc[i][j] = __builtin_amdgcn_mfma_f32_16x16x32_f16(af[i], bf[j], acc[i][j], 0, 0, 0);
    }

#pragma unroll
    for (int i = 0; i < 4; ++i)
#pragma unroll
        for (int r = 0; r < 4; ++r) {
            int row = m0 + wm + i * 16 + quad * 4 + r;
            float dd = dinv[row];  // 0 on pad rows
#pragma unroll
            for (int j = 0; j < 4; ++j) {
                int col = n0 + wn + j * 16 + lm;
                G[(size_t)row * DIM + col] = (_Float16)(dd * acc[i][j][r]);
            }
        }
}

// ---------------------------------------------------------------- aggregation
// XCD-affine feature-chunked gather (chunk = blockIdx&7 -> 2.57MB slab per XCD L2)
// + serial per-node edge loops: wave = 8 nodes x 64 features; each 8-lane octet
// owns one node (degree-sorted -> uniform trip counts), accumulates in registers.
// OutT = _Float16 for layer 1 (feeds GEMM2); OutT = float for layer 2 — the
// final output stays fp32 so CSR-order nondeterminism cannot flip large-ulp
// f16 values at the pooled maxima (the R9/R11 replay-divergence mechanism).
template <typename OutT>
__global__ __launch_bounds__(256) void k_agg_t(const _Float16* __restrict__ g,
                                               const float* __restrict__ dinv,
                                               const int* __restrict__ offs,
                                               const int* __restrict__ csr_src,
                                               const int* __restrict__ sorted,
                                               const float* __restrict__ bias,
                                               OutT* __restrict__ out) {
    int chunk = blockIdx.x & 7;
    int grp = blockIdx.x >> 3;                 // 0..627
    int w = threadIdx.x >> 6, lane = threadIdx.x & 63;
    int slot = lane >> 3, fg = lane & 7;
    int idx = grp * 32 + w * 8 + slot;         // 0..MP-1 exactly (628*32 = 20096)
    int node = sorted[idx];
    if ((unsigned)node >= (unsigned)MP) return;  // defensive: never scribble OOB
    int fbase = chunk * 64 + fg * 8;
    size_t obase = (size_t)node * DIM + fbase;

    if (node >= N_NODES) {  // pad row: zero this chunk (x1f feeds GEMM2's A)
        float z[8] = {0.f, 0.f, 0.f, 0.f, 0.f, 0.f, 0.f, 0.f};
        store8(&out[obase], z);
        return;
    }

    float acc[8];
    half8 self = *(const half8*)&g[obase];
#pragma unroll
    for (int i = 0; i < 8; ++i) acc[i] = (float)self[i];

    int beg = offs[node], end = offs[node + 1];
    int e = beg;
    for (; e + 8 <= end; e += 8) {
        int s0 = csr_src[e],     s1 = csr_src[e + 1], s2 = csr_src[e + 2], s3 = csr_src[e + 3];
        int s4 = csr_src[e + 4], s5 = csr_src[e + 5], s6 = csr_src[e + 6], s7 = csr_src[e + 7];
        half8 v0 = *(const half8*)&g[(size_t)s0 * DIM + fbase];
        half8 v1 = *(const half8*)&g[(size_t)s1 * DIM + fbase];
        half8 v2 = *(const half8*)&g[(size_t)s2 * DIM + fbase];
        half8 v3 = *(const half8*)&g[(size_t)s3 * DIM + fbase];
        half8 v4 = *(const half8*)&g[(size_t)s4 * DIM + fbase];
        half8 v5 = *(const half8*)&g[(size_t)s5 * DIM + fbase];
        half8 v6 = *(const half8*)&g[(size_t)s6 * DIM + fbase];
        half8 v7 = *(const half8*)&g[(size_t)s7 * DIM + fbase];
#pragma unroll
        for (int i = 0; i < 8; ++i)
            acc[i] += (((float)v0[i] + (float)v1[i]) + ((float)v2[i] + (float)v3[i])) +
                      (((float)v4[i] + (float)v5[i]) + ((float)v6[i] + (float)v7[i]));
    }
    for (; e + 4 <= end; e += 4) {
        int s0 = csr_src[e], s1 = csr_src[e + 1], s2 = csr_src[e + 2], s3 = csr_src[e + 3];
        half8 v0 = *(const half8*)&g[(size_t)s0 * DIM + fbase];
        half8 v1 = *(const half8*)&g[(size_t)s1 * DIM + fbase];
        half8 v2 = *(const half8*)&g[(size_t)s2 * DIM + fbase];
        half8 v3 = *(const half8*)&g[(size_t)s3 * DIM + fbase];
#pragma unroll
        for (int i = 0; i < 8; ++i)
            acc[i] += ((float)v0[i] + (float)v1[i]) + ((float)v2[i] + (float)v3[i]);
    }
    for (; e < end; ++e) {
        int s = csr_src[e];
        half8 v = *(const half8*)&g[(size_t)s * DIM + fbase];
#pragma unroll
        for (int i = 0; i < 8; ++i) acc[i] += (float)v[i];
    }

    float dd = dinv[node];
    float4 b0 = *(const float4*)&bias[fbase];
    float4 b1 = *(const float4*)&bias[fbase + 4];
    float bb[8] = {b0.x, b0.y, b0.z, b0.w, b1.x, b1.y, b1.z, b1.w};
    float o[8];
#pragma unroll
    for (int i = 0; i < 8; ++i) o[i] = fmaxf(fmaf(dd, acc[i], bb[i]), 0.f);
    store8(&out[obase], o);
}

// ---------------------------------------------------------------- max pool (fp32 in)
__global__ __launch_bounds__(256) void k_maxpool(const float* __restrict__ x,
                                                 float* __restrict__ out) {
    __shared__ float lmax[4][DIM];
    int stream = threadIdx.x >> 6, lane = threadIdx.x & 63;
    int f0 = lane * 8;
    int r0 = blockIdx.x * MAXP_ROWS;
    int r1 = min(r0 + MAXP_ROWS, N_NODES);

    float m[8];
#pragma unroll
    for (int i = 0; i < 8; ++i) m[i] = 0.f;
    for (int r = r0 + stream; r < r1; r += 4) {
        float4 a = *(const float4*)&x[(size_t)r * DIM + f0];
        float4 b = *(const float4*)&x[(size_t)r * DIM + f0 + 4];
        m[0] = fmaxf(m[0], a.x); m[1] = fmaxf(m[1], a.y);
        m[2] = fmaxf(m[2], a.z); m[3] = fmaxf(m[3], a.w);
        m[4] = fmaxf(m[4], b.x); m[5] = fmaxf(m[5], b.y);
        m[6] = fmaxf(m[6], b.z); m[7] = fmaxf(m[7], b.w);
    }
#pragma unroll
    for (int i = 0; i < 8; ++i) lmax[stream][f0 + i] = m[i];
    __syncthreads();
#pragma unroll
    for (int rep = 0; rep < 2; ++rep) {
        int f = rep * 256 + threadIdx.x;
        float v = fmaxf(fmaxf(lmax[0][f], lmax[1][f]), fmaxf(lmax[2][f], lmax[3][f]));
        atomicMax((int*)&out[f], __float_as_int(v));  // post-ReLU >= 0: int cmp == float cmp
    }
}

// ---------------------------------------------------------------- launch
extern "C" void kernel_launch(void* const* d_in, const int* in_sizes, int n_in,
                              void* d_out, int out_size, void* d_ws, size_t ws_size,
                              hipStream_t stream) {
    const float* features = (const float*)d_in[0];
    const int*   ei       = (const int*)d_in[1];
    const float* W1       = (const float*)d_in[3];
    const float* b1       = (const float*)d_in[4];
    const float* W2       = (const float*)d_in[5];
    const float* b2       = (const float*)d_in[6];
    float* out = (float*)d_out;

    const int* src = ei;
    const int* dst = ei + N_EDGES;

    char* p = (char*)d_ws;
    auto alloc = [&](size_t bytes) { void* r = p; p += (bytes + 255) & ~(size_t)255; return r; };
    // zero-region: cnt + hist + bincur (single memset)
    int*      cnt    = (int*)alloc(N_NODES * 4);
    int*      hist   = (int*)alloc(NBIN * 4);
    int*      bincur = (int*)alloc(NBIN * 4);
    char*     zeroEnd = p;
    int*      offs   = (int*)alloc((N_NODES + 1) * 4);
    int*      cursor = (int*)alloc(N_NODES * 4);
    float*    dinv   = (float*)alloc(MP * 4);
    int*      csr    = (int*)alloc(N_EDGES * 4);
    int*      bsum   = (int*)alloc(SCAN_BLOCKS * 4);
    int*      bbase  = (int*)alloc(SCAN_BLOCKS * 4);
    int*      sorted = (int*)alloc(MP * 4);
    _Float16* Wt1  = (_Float16*)alloc((size_t)DIM * DIM * 2);
    _Float16* Wt2  = (_Float16*)alloc((size_t)DIM * DIM * 2);
    _Float16* gbuf = (_Float16*)alloc((size_t)MP * DIM * 2);
    _Float16* x1f  = (_Float16*)alloc((size_t)MP * DIM * 2);
    float*    x2f  = (float*)alloc((size_t)MP * DIM * 4);   // fp32 final layer out

    // --- zero cnt/hist/bincur + out
    hipMemsetAsync(cnt, 0, (size_t)(zeroEnd - (char*)cnt), stream);
    hipMemsetAsync(out, 0, DIM * 4, stream);

    // --- graph norm + CSR build
    k_count<<<FILL_BLOCKS, 256, 0, stream>>>(dst, cnt);
    k_scan_a<<<SCAN_BLOCKS, 256, 0, stream>>>(cnt, bsum);
    k_scan_b<<<1, 128, 0, stream>>>(bsum, bbase);
    k_scan_c<<<SCAN_BLOCKS, 256, 0, stream>>>(cnt, bbase, offs, cursor, dinv, hist);

    // --- fused: CSR fill + W transposes + degree sort
    k_prep<<<FILL_BLOCKS + W_BLOCKS + SORT_BLOCKS, 256, 0, stream>>>(
        src, dst, cursor, csr, W1, W2, Wt1, Wt2, cnt, hist, bincur, sorted);

    dim3 ggrd(MP / 128, DIM / 128);

    // --- layer 1 (A = fp32 features, converted in staging; f16 out)
    k_gemm_f32A<<<ggrd, 256, 0, stream>>>(features, Wt1, dinv, gbuf);
    k_agg_t<_Float16><<<8 * (MP / 32), 256, 0, stream>>>(gbuf, dinv, offs, csr, sorted, b1, x1f);

    // --- layer 2 (A = f16 x1f; fp32 final out)
    k_gemm_f16<<<ggrd, 256, 0, stream>>>(x1f, Wt2, dinv, gbuf);
    k_agg_t<float><<<8 * (MP / 32), 256, 0, stream>>>(gbuf, dinv, offs, csr, sorted, b2, x2f);

    // --- global max pool (out zeroed by memset)
    k_maxpool<<<MAXP_BLOCKS, 256, 0, stream>>>(x2f, out);
}

// Round 13
// 250.166 us; speedup vs baseline: 1.0862x; 1.0862x over previous
//
#include <hip/hip_runtime.h>

#define N_NODES 20000
#define MP      20096   // N_NODES padded to multiple of 128
#define N_EDGES 320000
#define DIM     512
#define SCAN_BLOCKS 79    // ceil(20224/256)
#define FILL_BLOCKS 1250  // N_EDGES/256
#define W_BLOCKS    512   // 16x16 tiles x 2 weights
#define SORT_BLOCKS 79
#define NBIN 4096         // 256 degree bins x 16 sub-bins (shortens atomic chains)

typedef _Float16 half8 __attribute__((ext_vector_type(8)));
typedef float floatx4 __attribute__((ext_vector_type(4)));

#define GLD16(g, l) __builtin_amdgcn_global_load_lds( \
    (const __attribute__((address_space(1))) unsigned int*)(g), \
    (__attribute__((address_space(3))) unsigned int*)(l), 16, 0, 0)

__global__ void k_count(const int* __restrict__ dst, int* __restrict__ cnt) {
    int e = blockIdx.x * blockDim.x + threadIdx.x;
    if (e < N_EDGES) atomicAdd(&cnt[dst[e]], 1);
}

// ---------------------------------------------------------------- parallel scan
__global__ __launch_bounds__(256) void k_scan_a(const int* __restrict__ cnt,
                                                int* __restrict__ bsum) {
    __shared__ int buf[256];
    int gi = blockIdx.x * 256 + threadIdx.x;
    buf[threadIdx.x] = (gi < N_NODES) ? cnt[gi] : 0;
    __syncthreads();
    for (int off = 128; off > 0; off >>= 1) {
        if (threadIdx.x < off) buf[threadIdx.x] += buf[threadIdx.x + off];
        __syncthreads();
    }
    if (threadIdx.x == 0) bsum[blockIdx.x] = buf[0];
}

__global__ __launch_bounds__(128) void k_scan_b(const int* __restrict__ bsum,
                                                int* __restrict__ bbase) {
    __shared__ int buf[128];
    int tid = threadIdx.x;
    int v = (tid < SCAN_BLOCKS) ? bsum[tid] : 0;
    buf[tid] = v;
    __syncthreads();
    for (int off = 1; off < 128; off <<= 1) {
        int t = (tid >= off) ? buf[tid - off] : 0;
        __syncthreads();
        buf[tid] += t;
        __syncthreads();
    }
    if (tid < SCAN_BLOCKS) bbase[tid] = buf[tid] - v;  // exclusive
}

// offs/cursor/dinv + sub-binned degree histogram (for the counting sort)
__global__ __launch_bounds__(256) void k_scan_c(const int* __restrict__ cnt,
                                                const int* __restrict__ bbase,
                                                int* __restrict__ offs,
                                                int* __restrict__ cursor,
                                                float* __restrict__ dinv,
                                                int* __restrict__ hist) {
    __shared__ int buf[256];
    __shared__ int lh[NBIN];
    int tid = threadIdx.x;
#pragma unroll
    for (int k = 0; k < NBIN / 256; ++k) lh[tid + k * 256] = 0;
    int gi = blockIdx.x * 256 + tid;
    int v = (gi < N_NODES) ? cnt[gi] : 0;
    buf[tid] = v;
    __syncthreads();
    for (int off = 1; off < 256; off <<= 1) {
        int t = (tid >= off) ? buf[tid - off] : 0;
        __syncthreads();
        buf[tid] += t;
        __syncthreads();
    }
    int base = bbase[blockIdx.x];
    if (gi < N_NODES) {
        int incl = base + buf[tid];
        offs[gi + 1] = incl;
        cursor[gi] = incl - v;
        dinv[gi] = rsqrtf((float)v + 1.0f);  // +1 self-loop
        if (gi == 0) offs[0] = 0;
        int bin = (v > 255 ? 255 : v) * 16 + (gi & 15);
        atomicAdd(&lh[bin], 1);
    } else if (gi < MP) {
        dinv[gi] = 0.f;  // pad rows: zero (poison-proofs GEMM epilogue)
    }
    __syncthreads();
#pragma unroll
    for (int k = 0; k < NBIN / 256; ++k) {
        int b2 = tid + k * 256;
        if (lh[b2]) atomicAdd(&hist[b2], lh[b2]);
    }
}

// ---------------------------------------------------------------- fused prep
// [0,1250): CSR fill; [1250,1762): W transpose; [1762,1841): counting-sort
// scatter (single-level atomic form, 16 sub-bins). Sort order is a perf
// heuristic only — correctness never depends on it.
__global__ __launch_bounds__(256) void k_prep(const int* __restrict__ src,
                                              const int* __restrict__ dst,
                                              int* __restrict__ cursor,
                                              int* __restrict__ csr_src,
                                              const float* __restrict__ W1,
                                              const float* __restrict__ W2,
                                              _Float16* __restrict__ Wt1,
                                              _Float16* __restrict__ Wt2,
                                              const int* __restrict__ cnt,
                                              const int* __restrict__ hist,
                                              int* __restrict__ bincur,
                                              int* __restrict__ sorted) {
    int b = blockIdx.x;
    if (b < FILL_BLOCKS) {
        int e = b * 256 + threadIdx.x;
        int d = dst[e];
        int pos = atomicAdd(&cursor[d], 1);
        csr_src[pos] = src[e];
        return;
    }
    if (b < FILL_BLOCKS + W_BLOCKS) {
        // W transpose: fp32 [k][n] -> f16 [n][k]
        int local = b - FILL_BLOCKS;
        int z = local >> 8, t = local & 255;
        const float* W = z ? W2 : W1;
        _Float16* Wt = z ? Wt2 : Wt1;
        __shared__ float tile[32][33];
        int bx = (t & 15) * 32, by = (t >> 4) * 32;
        int x = threadIdx.x & 31, y4 = (threadIdx.x >> 5) * 4;
#pragma unroll
        for (int r = 0; r < 4; ++r)
            tile[y4 + r][x] = W[(size_t)(by + y4 + r) * DIM + bx + x];
        __syncthreads();
#pragma unroll
        for (int r = 0; r < 4; ++r)
            Wt[(size_t)(bx + y4 + r) * DIM + by + x] = (_Float16)tile[x][y4 + r];
        return;
    }
    // --- counting-sort scatter (single-level, R10/R12-proven)
    int sb = b - (FILL_BLOCKS + W_BLOCKS);
    __shared__ int sc[NBIN];  // global exclusive base per bin
    __shared__ int ps[256];
    int tid = threadIdx.x;
    int tsum = 0;
#pragma unroll
    for (int k = 0; k < NBIN / 256; ++k) {
        int h = hist[tid * (NBIN / 256) + k];
        sc[tid * (NBIN / 256) + k] = tsum;  // exclusive within this thread's group
        tsum += h;
    }
    ps[tid] = tsum;
    __syncthreads();
    for (int off = 1; off < 256; off <<= 1) {
        int t = (tid >= off) ? ps[tid - off] : 0;
        __syncthreads();
        ps[tid] += t;
        __syncthreads();
    }
    int gbase = ps[tid] - tsum;  // exclusive prefix of this thread's bin group
#pragma unroll
    for (int k = 0; k < NBIN / 256; ++k) sc[tid * (NBIN / 256) + k] += gbase;
    __syncthreads();
    int gi = sb * 256 + tid;
    if (gi < N_NODES) {
        int d = cnt[gi];
        int bin = (d > 255 ? 255 : d) * 16 + (gi & 15);
        int pos = sc[bin] + atomicAdd(&bincur[bin], 1);
        sorted[pos] = gi;
    } else if (gi < MP) {
        sorted[gi] = gi;  // pad ids land at [N_NODES, MP)
    }
}

// ---------------------------------------------------------------- MFMA GEMM (f16 A)
// g[MP,512] f16 = dinv[row] * (A[MP,512] f16 @ Bt[n][k] f16)
__global__ __launch_bounds__(256) void k_gemm_f16(const _Float16* __restrict__ A,
                                                  const _Float16* __restrict__ Bt,
                                                  const float* __restrict__ dinv,
                                                  _Float16* __restrict__ G) {
    __shared__ _Float16 As[128 * 32];  // [m][k], k contiguous
    __shared__ _Float16 Bs[128 * 32];  // [n][k], k contiguous

    int t = threadIdx.x;
    int w = t >> 6, lane = t & 63;
    int lm = lane & 15, quad = lane >> 4;
    int m0 = blockIdx.x * 128, n0 = blockIdx.y * 128;
    int wm = (w & 1) * 64, wn = (w >> 1) * 64;

    floatx4 acc[4][4];
#pragma unroll
    for (int i = 0; i < 4; ++i)
#pragma unroll
        for (int j = 0; j < 4; ++j) acc[i][j] = (floatx4){0.f, 0.f, 0.f, 0.f};

    for (int k0 = 0; k0 < DIM; k0 += 32) {
        __syncthreads();
#pragma unroll
        for (int i = 0; i < 2; ++i) {
            int s = i * 256 + t;
            int m = s >> 2, kk = (s & 3) * 8;
            GLD16(A + (size_t)(m0 + m) * DIM + k0 + kk, As + s * 8);
            GLD16(Bt + (size_t)(n0 + m) * DIM + k0 + kk, Bs + s * 8);
        }
        __syncthreads();

        half8 af[4], bf[4];
#pragma unroll
        for (int i = 0; i < 4; ++i)
            af[i] = *(const half8*)&As[(wm + i * 16 + lm) * 32 + quad * 8];
#pragma unroll
        for (int j = 0; j < 4; ++j)
            bf[j] = *(const half8*)&Bs[(wn + j * 16 + lm) * 32 + quad * 8];
#pragma unroll
        for (int i = 0; i < 4; ++i)
#pragma unroll
            for (int j = 0; j < 4; ++j)
                acc[i][j] = __builtin_amdgcn_mfma_f32_16x16x32_f16(af[i], bf[j], acc[i][j], 0, 0, 0);
    }

#pragma unroll
    for (int i = 0; i < 4; ++i)
#pragma unroll
        for (int r = 0; r < 4; ++r) {
            int row = m0 + wm + i * 16 + quad * 4 + r;
            float dd = dinv[row];  // 0 on pad rows
#pragma unroll
            for (int j = 0; j < 4; ++j) {
                int col = n0 + wn + j * 16 + lm;
                G[(size_t)row * DIM + col] = (_Float16)(dd * acc[i][j][r]);
            }
        }
}

// ---------------------------------------------------------------- MFMA GEMM (fp32 A, pipelined)
// Layer 1: reads features fp32 directly; A-prefetch into registers is placed
// textually after the MFMA stage so the loads overlap compute; the cvt+ds_write
// happens at the next loop top from registers. Rows >= N_NODES staged as zero.
__global__ __launch_bounds__(256) void k_gemm_f32A(const float* __restrict__ A,
                                                   const _Float16* __restrict__ Bt,
                                                   const float* __restrict__ dinv,
                                                   _Float16* __restrict__ G) {
    __shared__ _Float16 As[128 * 32];  // [m][k], k contiguous
    __shared__ _Float16 Bs[128 * 32];  // [n][k], k contiguous

    int t = threadIdx.x;
    int w = t >> 6, lane = t & 63;
    int lm = lane & 15, quad = lane >> 4;
    int m0 = blockIdx.x * 128, n0 = blockIdx.y * 128;
    int wm = (w & 1) * 64, wn = (w >> 1) * 64;

    // this thread's two A segments (fixed across k-iterations)
    int s0 = t, s1 = 256 + t;
    int am0 = s0 >> 2, ak0 = (s0 & 3) * 8;
    int am1 = s1 >> 2, ak1 = (s1 & 3) * 8;
    bool v0 = (m0 + am0) < N_NODES;
    bool v1 = (m0 + am1) < N_NODES;
    const float* ap0 = A + (size_t)(m0 + am0) * DIM + ak0;
    const float* ap1 = A + (size_t)(m0 + am1) * DIM + ak1;

    floatx4 acc[4][4];
#pragma unroll
    for (int i = 0; i < 4; ++i)
#pragma unroll
        for (int j = 0; j < 4; ++j) acc[i][j] = (floatx4){0.f, 0.f, 0.f, 0.f};

    float4 z4 = make_float4(0.f, 0.f, 0.f, 0.f);
    float4 p0a = z4, p0b = z4, p1a = z4, p1b = z4;
    if (v0) { p0a = *(const float4*)(ap0); p0b = *(const float4*)(ap0 + 4); }
    if (v1) { p1a = *(const float4*)(ap1); p1b = *(const float4*)(ap1 + 4); }

    for (int k0 = 0; k0 < DIM; k0 += 32) {
        __syncthreads();  // prior-iteration LDS reads complete
#pragma unroll
        for (int i = 0; i < 2; ++i) {  // B: async direct-to-LDS
            int s = i * 256 + t;
            int m = s >> 2, kk = (s & 3) * 8;
            GLD16(Bt + (size_t)(n0 + m) * DIM + k0 + kk, Bs + s * 8);
        }
        {  // A: cvt prefetched regs -> LDS
            half8 h0, h1;
            h0[0] = (_Float16)p0a.x; h0[1] = (_Float16)p0a.y;
            h0[2] = (_Float16)p0a.z; h0[3] = (_Float16)p0a.w;
            h0[4] = (_Float16)p0b.x; h0[5] = (_Float16)p0b.y;
            h0[6] = (_Float16)p0b.z; h0[7] = (_Float16)p0b.w;
            h1[0] = (_Float16)p1a.x; h1[1] = (_Float16)p1a.y;
            h1[2] = (_Float16)p1a.z; h1[3] = (_Float16)p1a.w;
            h1[4] = (_Float16)p1b.x; h1[5] = (_Float16)p1b.y;
            h1[6] = (_Float16)p1b.z; h1[7] = (_Float16)p1b.w;
            *(half8*)&As[s0 * 8] = h0;
            *(half8*)&As[s1 * 8] = h1;
        }
        __syncthreads();  // staging drained

        half8 af[4], bf[4];
#pragma unroll
        for (int i = 0; i < 4; ++i)
            af[i] = *(const half8*)&As[(wm + i * 16 + lm) * 32 + quad * 8];
#pragma unroll
        for (int j = 0; j < 4; ++j)
            bf[j] = *(const half8*)&Bs[(wn + j * 16 + lm) * 32 + quad * 8];
#pragma unroll
        for (int i = 0; i < 4; ++i)
#pragma unroll
            for (int j = 0; j < 4; ++j)
                acc[i][j] = __builtin_amdgcn_mfma_f32_16x16x32_f16(af[i], bf[j], acc[i][j], 0, 0, 0);

        // prefetch next k-tile's A (overlaps the MFMA stage; drained at next top barrier)
        int kn = k0 + 32;
        if (kn < DIM) {
            if (v0) { p0a = *(const float4*)(ap0 + kn); p0b = *(const float4*)(ap0 + kn + 4); }
            if (v1) { p1a = *(const float4*)(ap1 + kn); p1b = *(const float4*)(ap1 + kn + 4); }
        }
    }

#pragma unroll
    for (int i = 0; i < 4; ++i)
#pragma unroll
        for (int r = 0; r < 4; ++r) {
            int row = m0 + wm + i * 16 + quad * 4 + r;
            float dd = dinv[row];  // 0 on pad rows
#pragma unroll
            for (int j = 0; j < 4; ++j) {
                int col = n0 + wn + j * 16 + lm;
                G[(size_t)row * DIM + col] = (_Float16)(dd * acc[i][j][r]);
            }
        }
}

// ---------------------------------------------------------------- agg layer 1 (f16 out)
// XCD-affine feature-chunked gather (chunk = blockIdx&7 -> 2.57MB slab per XCD L2)
// + serial per-node edge loops: wave = 8 nodes x 64 features; each 8-lane octet
// owns one node (degree-sorted -> uniform trip counts), accumulates in registers.
__global__ __launch_bounds__(256) void k_agg1(const _Float16* __restrict__ g,
                                              const float* __restrict__ dinv,
                                              const int* __restrict__ offs,
                                              const int* __restrict__ csr_src,
                                              const int* __restrict__ sorted,
                                              const float* __restrict__ bias,
                                              _Float16* __restrict__ out) {
    int chunk = blockIdx.x & 7;
    int grp = blockIdx.x >> 3;
    int w = threadIdx.x >> 6, lane = threadIdx.x & 63;
    int slot = lane >> 3, fg = lane & 7;
    int idx = grp * 32 + w * 8 + slot;         // 0..MP-1 exactly (628*32 = 20096)
    int node = sorted[idx];
    if ((unsigned)node >= (unsigned)MP) return;  // defensive: never scribble OOB
    int fbase = chunk * 64 + fg * 8;
    size_t obase = (size_t)node * DIM + fbase;

    if (node >= N_NODES) {  // pad row: zero this 16B (x1f feeds GEMM2's A)
        half8 z;
#pragma unroll
        for (int i = 0; i < 8; ++i) z[i] = (_Float16)0.f;
        *(half8*)&out[obase] = z;
        return;
    }

    float acc[8];
    half8 self = *(const half8*)&g[obase];
#pragma unroll
    for (int i = 0; i < 8; ++i) acc[i] = (float)self[i];

    int beg = offs[node], end = offs[node + 1];
    int e = beg;
    for (; e + 8 <= end; e += 8) {
        int s0 = csr_src[e],     s1 = csr_src[e + 1], s2 = csr_src[e + 2], s3 = csr_src[e + 3];
        int s4 = csr_src[e + 4], s5 = csr_src[e + 5], s6 = csr_src[e + 6], s7 = csr_src[e + 7];
        half8 v0 = *(const half8*)&g[(size_t)s0 * DIM + fbase];
        half8 v1 = *(const half8*)&g[(size_t)s1 * DIM + fbase];
        half8 v2 = *(const half8*)&g[(size_t)s2 * DIM + fbase];
        half8 v3 = *(const half8*)&g[(size_t)s3 * DIM + fbase];
        half8 v4 = *(const half8*)&g[(size_t)s4 * DIM + fbase];
        half8 v5 = *(const half8*)&g[(size_t)s5 * DIM + fbase];
        half8 v6 = *(const half8*)&g[(size_t)s6 * DIM + fbase];
        half8 v7 = *(const half8*)&g[(size_t)s7 * DIM + fbase];
#pragma unroll
        for (int i = 0; i < 8; ++i)
            acc[i] += (((float)v0[i] + (float)v1[i]) + ((float)v2[i] + (float)v3[i])) +
                      (((float)v4[i] + (float)v5[i]) + ((float)v6[i] + (float)v7[i]));
    }
    for (; e + 4 <= end; e += 4) {
        int s0 = csr_src[e], s1 = csr_src[e + 1], s2 = csr_src[e + 2], s3 = csr_src[e + 3];
        half8 v0 = *(const half8*)&g[(size_t)s0 * DIM + fbase];
        half8 v1 = *(const half8*)&g[(size_t)s1 * DIM + fbase];
        half8 v2 = *(const half8*)&g[(size_t)s2 * DIM + fbase];
        half8 v3 = *(const half8*)&g[(size_t)s3 * DIM + fbase];
#pragma unroll
        for (int i = 0; i < 8; ++i)
            acc[i] += ((float)v0[i] + (float)v1[i]) + ((float)v2[i] + (float)v3[i]);
    }
    for (; e < end; ++e) {
        int s = csr_src[e];
        half8 v = *(const half8*)&g[(size_t)s * DIM + fbase];
#pragma unroll
        for (int i = 0; i < 8; ++i) acc[i] += (float)v[i];
    }

    float dd = dinv[node];
    float4 b0 = *(const float4*)&bias[fbase];
    float4 b1 = *(const float4*)&bias[fbase + 4];
    float bb[8] = {b0.x, b0.y, b0.z, b0.w, b1.x, b1.y, b1.z, b1.w};
    half8 o;
#pragma unroll
    for (int i = 0; i < 8; ++i) o[i] = (_Float16)fmaxf(fmaf(dd, acc[i], bb[i]), 0.f);
    *(half8*)&out[obase] = o;
}

// ---------------------------------------------------------------- agg layer 2 + fused max-pool
// Same gather structure, but the per-node result never hits memory: block-level
// LDS max-reduction over the 32 nodes, then one atomicMax per feature per block
// into d_out. Pool operates on fp32 values (replay-stable: no f16 ulp flips at
// maxima). No early returns — every thread reaches the barrier.
__global__ __launch_bounds__(256) void k_agg_pool(const _Float16* __restrict__ g,
                                                  const float* __restrict__ dinv,
                                                  const int* __restrict__ offs,
                                                  const int* __restrict__ csr_src,
                                                  const int* __restrict__ sorted,
                                                  const float* __restrict__ bias,
                                                  float* __restrict__ out) {
    __shared__ float lmax[32 * 68];  // 32 node-rows x 64 feats, stride 68 (2-way banks = free)
    int chunk = blockIdx.x & 7;
    int grp = blockIdx.x >> 3;
    int w = threadIdx.x >> 6, lane = threadIdx.x & 63;
    int slot = lane >> 3, fg = lane & 7;
    int idx = grp * 32 + w * 8 + slot;
    int node = sorted[idx];
    int fbase = chunk * 64 + fg * 8;
    bool valid = ((unsigned)node < (unsigned)N_NODES);

    float o[8];
#pragma unroll
    for (int i = 0; i < 8; ++i) o[i] = 0.f;

    if (valid) {
        size_t obase = (size_t)node * DIM + fbase;
        float acc[8];
        half8 self = *(const half8*)&g[obase];
#pragma unroll
        for (int i = 0; i < 8; ++i) acc[i] = (float)self[i];

        int beg = offs[node], end = offs[node + 1];
        int e = beg;
        for (; e + 8 <= end; e += 8) {
            int s0 = csr_src[e],     s1 = csr_src[e + 1], s2 = csr_src[e + 2], s3 = csr_src[e + 3];
            int s4 = csr_src[e + 4], s5 = csr_src[e + 5], s6 = csr_src[e + 6], s7 = csr_src[e + 7];
            half8 v0 = *(const half8*)&g[(size_t)s0 * DIM + fbase];
            half8 v1 = *(const half8*)&g[(size_t)s1 * DIM + fbase];
            half8 v2 = *(const half8*)&g[(size_t)s2 * DIM + fbase];
            half8 v3 = *(const half8*)&g[(size_t)s3 * DIM + fbase];
            half8 v4 = *(const half8*)&g[(size_t)s4 * DIM + fbase];
            half8 v5 = *(const half8*)&g[(size_t)s5 * DIM + fbase];
            half8 v6 = *(const half8*)&g[(size_t)s6 * DIM + fbase];
            half8 v7 = *(const half8*)&g[(size_t)s7 * DIM + fbase];
#pragma unroll
            for (int i = 0; i < 8; ++i)
                o[i] = (((float)v0[i] + (float)v1[i]) + ((float)v2[i] + (float)v3[i])) +
                       (((float)v4[i] + (float)v5[i]) + ((float)v6[i] + (float)v7[i]));
#pragma unroll
            for (int i = 0; i < 8; ++i) acc[i] += o[i];
        }
        for (; e + 4 <= end; e += 4) {
            int s0 = csr_src[e], s1 = csr_src[e + 1], s2 = csr_src[e + 2], s3 = csr_src[e + 3];
            half8 v0 = *(const half8*)&g[(size_t)s0 * DIM + fbase];
            half8 v1 = *(const half8*)&g[(size_t)s1 * DIM + fbase];
            half8 v2 = *(const half8*)&g[(size_t)s2 * DIM + fbase];
            half8 v3 = *(const half8*)&g[(size_t)s3 * DIM + fbase];
#pragma unroll
            for (int i = 0; i < 8; ++i)
                acc[i] += ((float)v0[i] + (float)v1[i]) + ((float)v2[i] + (float)v3[i]);
        }
        for (; e < end; ++e) {
            int s = csr_src[e];
            half8 v = *(const half8*)&g[(size_t)s * DIM + fbase];
#pragma unroll
            for (int i = 0; i < 8; ++i) acc[i] += (float)v[i];
        }

        float dd = dinv[node];
        float4 b0 = *(const float4*)&bias[fbase];
        float4 b1 = *(const float4*)&bias[fbase + 4];
        float bb[8] = {b0.x, b0.y, b0.z, b0.w, b1.x, b1.y, b1.z, b1.w};
#pragma unroll
        for (int i = 0; i < 8; ++i) o[i] = fmaxf(fmaf(dd, acc[i], bb[i]), 0.f);
    }

    // block max-reduce over 32 nodes
    int row = w * 8 + slot;
#pragma unroll
    for (int i = 0; i < 8; ++i) lmax[row * 68 + fg * 8 + i] = o[i];
    __syncthreads();
    if (threadIdx.x < 64) {
        int c = threadIdx.x;
        float m = 0.f;
#pragma unroll
        for (int r = 0; r < 32; ++r) m = fmaxf(m, lmax[r * 68 + c]);
        atomicMax((int*)&out[chunk * 64 + c], __float_as_int(m));  // post-ReLU >= 0
    }
}

// ---------------------------------------------------------------- launch
extern "C" void kernel_launch(void* const* d_in, const int* in_sizes, int n_in,
                              void* d_out, int out_size, void* d_ws, size_t ws_size,
                              hipStream_t stream) {
    const float* features = (const float*)d_in[0];
    const int*   ei       = (const int*)d_in[1];
    const float* W1       = (const float*)d_in[3];
    const float* b1       = (const float*)d_in[4];
    const float* W2       = (const float*)d_in[5];
    const float* b2       = (const float*)d_in[6];
    float* out = (float*)d_out;

    const int* src = ei;
    const int* dst = ei + N_EDGES;

    char* p = (char*)d_ws;
    auto alloc = [&](size_t bytes) { void* r = p; p += (bytes + 255) & ~(size_t)255; return r; };
    // zero-region: cnt + hist + bincur (single memset)
    int*      cnt    = (int*)alloc(N_NODES * 4);
    int*      hist   = (int*)alloc(NBIN * 4);
    int*      bincur = (int*)alloc(NBIN * 4);
    char*     zeroEnd = p;
    int*      offs   = (int*)alloc((N_NODES + 1) * 4);
    int*      cursor = (int*)alloc(N_NODES * 4);
    float*    dinv   = (float*)alloc(MP * 4);
    int*      csr    = (int*)alloc(N_EDGES * 4);
    int*      bsum   = (int*)alloc(SCAN_BLOCKS * 4);
    int*      bbase  = (int*)alloc(SCAN_BLOCKS * 4);
    int*      sorted = (int*)alloc(MP * 4);
    _Float16* Wt1  = (_Float16*)alloc((size_t)DIM * DIM * 2);
    _Float16* Wt2  = (_Float16*)alloc((size_t)DIM * DIM * 2);
    _Float16* gbuf = (_Float16*)alloc((size_t)MP * DIM * 2);
    _Float16* x1f  = (_Float16*)alloc((size_t)MP * DIM * 2);

    // --- zero cnt/hist/bincur + out
    hipMemsetAsync(cnt, 0, (size_t)(zeroEnd - (char*)cnt), stream);
    hipMemsetAsync(out, 0, DIM * 4, stream);

    // --- graph norm + CSR build
    k_count<<<FILL_BLOCKS, 256, 0, stream>>>(dst, cnt);
    k_scan_a<<<SCAN_BLOCKS, 256, 0, stream>>>(cnt, bsum);
    k_scan_b<<<1, 128, 0, stream>>>(bsum, bbase);
    k_scan_c<<<SCAN_BLOCKS, 256, 0, stream>>>(cnt, bbase, offs, cursor, dinv, hist);

    // --- fused: CSR fill + W transposes + degree sort
    k_prep<<<FILL_BLOCKS + W_BLOCKS + SORT_BLOCKS, 256, 0, stream>>>(
        src, dst, cursor, csr, W1, W2, Wt1, Wt2, cnt, hist, bincur, sorted);

    dim3 ggrd(MP / 128, DIM / 128);

    // --- layer 1 (A = fp32 features, pipelined staging; f16 out)
    k_gemm_f32A<<<ggrd, 256, 0, stream>>>(features, Wt1, dinv, gbuf);
    k_agg1<<<8 * (MP / 32), 256, 0, stream>>>(gbuf, dinv, offs, csr, sorted, b1, x1f);

    // --- layer 2 (A = f16 x1f) + fused fp32 max-pool into d_out
    k_gemm_f16<<<ggrd, 256, 0, stream>>>(x1f, Wt2, dinv, gbuf);
    k_agg_pool<<<8 * (MP / 32), 256, 0, stream>>>(gbuf, dinv, offs, csr, sorted, b2, out);
}

// Round 14
// 245.454 us; speedup vs baseline: 1.1070x; 1.0192x over previous
//
#include <hip/hip_runtime.h>

#define N_NODES 20000
#define MP      20096   // N_NODES padded to multiple of 128
#define N_EDGES 320000
#define DIM     512
#define SCAN_BLOCKS 79    // ceil(20224/256)
#define FILL_BLOCKS 1250  // N_EDGES/256
#define W_BLOCKS    512   // 16x16 tiles x 2 weights
#define SORT_BLOCKS 79
#define NBIN 4096         // 256 degree bins x 16 sub-bins (shortens atomic chains)

typedef _Float16 half8 __attribute__((ext_vector_type(8)));
typedef _Float16 half2v __attribute__((ext_vector_type(2)));
typedef float floatx4 __attribute__((ext_vector_type(4)));

#define GLD16(g, l) __builtin_amdgcn_global_load_lds( \
    (const __attribute__((address_space(1))) unsigned int*)(g), \
    (__attribute__((address_space(3))) unsigned int*)(l), 16, 0, 0)

// acc += a[i] + b[i] via v_dot2_f32_f16 (f32 accumulate, halves VALU vs cvt+add)
__device__ inline float dot2sum(_Float16 a, _Float16 b, float acc) {
    half2v p; p[0] = a; p[1] = b;
    half2v ones; ones[0] = (_Float16)1.0f; ones[1] = (_Float16)1.0f;
    return __builtin_amdgcn_fdot2(p, ones, acc, false);
}

__global__ void k_count(const int* __restrict__ dst, int* __restrict__ cnt) {
    int e = blockIdx.x * blockDim.x + threadIdx.x;
    if (e < N_EDGES) atomicAdd(&cnt[dst[e]], 1);
}

// ---------------------------------------------------------------- parallel scan
__global__ __launch_bounds__(256) void k_scan_a(const int* __restrict__ cnt,
                                                int* __restrict__ bsum) {
    __shared__ int buf[256];
    int gi = blockIdx.x * 256 + threadIdx.x;
    buf[threadIdx.x] = (gi < N_NODES) ? cnt[gi] : 0;
    __syncthreads();
    for (int off = 128; off > 0; off >>= 1) {
        if (threadIdx.x < off) buf[threadIdx.x] += buf[threadIdx.x + off];
        __syncthreads();
    }
    if (threadIdx.x == 0) bsum[blockIdx.x] = buf[0];
}

// offs/cursor/dinv + sub-binned degree histogram. The 79-partial exclusive scan
// (old k_scan_b) is folded in: every block redundantly scans bsum in LDS.
__global__ __launch_bounds__(256) void k_scan_c(const int* __restrict__ cnt,
                                                const int* __restrict__ bsum,
                                                int* __restrict__ offs,
                                                int* __restrict__ cursor,
                                                float* __restrict__ dinv,
                                                int* __restrict__ hist) {
    __shared__ int buf[256];
    __shared__ int sb[128];
    __shared__ int lh[NBIN];
    int tid = threadIdx.x;
#pragma unroll
    for (int k = 0; k < NBIN / 256; ++k) lh[tid + k * 256] = 0;
    if (tid < 128) sb[tid] = (tid < SCAN_BLOCKS) ? bsum[tid] : 0;
    int gi = blockIdx.x * 256 + tid;
    int v = (gi < N_NODES) ? cnt[gi] : 0;
    buf[tid] = v;
    __syncthreads();
    for (int off = 1; off < 256; off <<= 1) {
        int t = (tid >= off) ? buf[tid - off] : 0;
        int t2 = (tid < 128 && tid >= off && off < 128) ? sb[tid - off] : 0;
        __syncthreads();
        buf[tid] += t;
        if (tid < 128 && off < 128) sb[tid] += t2;
        __syncthreads();
    }
    int base = (blockIdx.x == 0) ? 0 : sb[blockIdx.x - 1];  // exclusive block base
    if (gi < N_NODES) {
        int incl = base + buf[tid];
        offs[gi + 1] = incl;
        cursor[gi] = incl - v;
        dinv[gi] = rsqrtf((float)v + 1.0f);  // +1 self-loop
        if (gi == 0) offs[0] = 0;
        int bin = (v > 255 ? 255 : v) * 16 + (gi & 15);
        atomicAdd(&lh[bin], 1);
    } else if (gi < MP) {
        dinv[gi] = 0.f;  // pad rows: zero (poison-proofs GEMM epilogue)
    }
    __syncthreads();
#pragma unroll
    for (int k = 0; k < NBIN / 256; ++k) {
        int b2 = tid + k * 256;
        if (lh[b2]) atomicAdd(&hist[b2], lh[b2]);
    }
}

// ---------------------------------------------------------------- fused prep
// [0,1250): CSR fill; [1250,1762): W transpose; [1762,1841): counting-sort
// scatter (single-level atomic form, 16 sub-bins). Sort order is a perf
// heuristic only — correctness never depends on it.
__global__ __launch_bounds__(256) void k_prep(const int* __restrict__ src,
                                              const int* __restrict__ dst,
                                              int* __restrict__ cursor,
                                              int* __restrict__ csr_src,
                                              const float* __restrict__ W1,
                                              const float* __restrict__ W2,
                                              _Float16* __restrict__ Wt1,
                                              _Float16* __restrict__ Wt2,
                                              const int* __restrict__ cnt,
                                              const int* __restrict__ hist,
                                              int* __restrict__ bincur,
                                              int* __restrict__ sorted) {
    int b = blockIdx.x;
    if (b < FILL_BLOCKS) {
        int e = b * 256 + threadIdx.x;
        int d = dst[e];
        int pos = atomicAdd(&cursor[d], 1);
        csr_src[pos] = src[e];
        return;
    }
    if (b < FILL_BLOCKS + W_BLOCKS) {
        // W transpose: fp32 [k][n] -> f16 [n][k]
        int local = b - FILL_BLOCKS;
        int z = local >> 8, t = local & 255;
        const float* W = z ? W2 : W1;
        _Float16* Wt = z ? Wt2 : Wt1;
        __shared__ float tile[32][33];
        int bx = (t & 15) * 32, by = (t >> 4) * 32;
        int x = threadIdx.x & 31, y4 = (threadIdx.x >> 5) * 4;
#pragma unroll
        for (int r = 0; r < 4; ++r)
            tile[y4 + r][x] = W[(size_t)(by + y4 + r) * DIM + bx + x];
        __syncthreads();
#pragma unroll
        for (int r = 0; r < 4; ++r)
            Wt[(size_t)(bx + y4 + r) * DIM + by + x] = (_Float16)tile[x][y4 + r];
        return;
    }
    // --- counting-sort scatter (single-level, R10/R12/R13-proven)
    int sb = b - (FILL_BLOCKS + W_BLOCKS);
    __shared__ int sc[NBIN];  // global exclusive base per bin
    __shared__ int ps[256];
    int tid = threadIdx.x;
    int tsum = 0;
#pragma unroll
    for (int k = 0; k < NBIN / 256; ++k) {
        int h = hist[tid * (NBIN / 256) + k];
        sc[tid * (NBIN / 256) + k] = tsum;  // exclusive within this thread's group
        tsum += h;
    }
    ps[tid] = tsum;
    __syncthreads();
    for (int off = 1; off < 256; off <<= 1) {
        int t = (tid >= off) ? ps[tid - off] : 0;
        __syncthreads();
        ps[tid] += t;
        __syncthreads();
    }
    int gbase = ps[tid] - tsum;  // exclusive prefix of this thread's bin group
#pragma unroll
    for (int k = 0; k < NBIN / 256; ++k) sc[tid * (NBIN / 256) + k] += gbase;
    __syncthreads();
    int gi = sb * 256 + tid;
    if (gi < N_NODES) {
        int d = cnt[gi];
        int bin = (d > 255 ? 255 : d) * 16 + (gi & 15);
        int pos = sc[bin] + atomicAdd(&bincur[bin], 1);
        sorted[pos] = gi;
    } else if (gi < MP) {
        sorted[gi] = gi;  // pad ids land at [N_NODES, MP)
    }
}

// ---------------------------------------------------------------- MFMA GEMM (f16 A)
// g[MP,512] f16 = dinv[row] * (A[MP,512] f16 @ Bt[n][k] f16)
__global__ __launch_bounds__(256) void k_gemm_f16(const _Float16* __restrict__ A,
                                                  const _Float16* __restrict__ Bt,
                                                  const float* __restrict__ dinv,
                                                  _Float16* __restrict__ G) {
    __shared__ _Float16 As[128 * 32];  // [m][k], k contiguous
    __shared__ _Float16 Bs[128 * 32];  // [n][k], k contiguous

    int t = threadIdx.x;
    int w = t >> 6, lane = t & 63;
    int lm = lane & 15, quad = lane >> 4;
    int m0 = blockIdx.x * 128, n0 = blockIdx.y * 128;
    int wm = (w & 1) * 64, wn = (w >> 1) * 64;

    floatx4 acc[4][4];
#pragma unroll
    for (int i = 0; i < 4; ++i)
#pragma unroll
        for (int j = 0; j < 4; ++j) acc[i][j] = (floatx4){0.f, 0.f, 0.f, 0.f};

    for (int k0 = 0; k0 < DIM; k0 += 32) {
        __syncthreads();
#pragma unroll
        for (int i = 0; i < 2; ++i) {
            int s = i * 256 + t;
            int m = s >> 2, kk = (s & 3) * 8;
            GLD16(A + (size_t)(m0 + m) * DIM + k0 + kk, As + s * 8);
            GLD16(Bt + (size_t)(n0 + m) * DIM + k0 + kk, Bs + s * 8);
        }
        __syncthreads();

        half8 af[4], bf[4];
#pragma unroll
        for (int i = 0; i < 4; ++i)
            af[i] = *(const half8*)&As[(wm + i * 16 + lm) * 32 + quad * 8];
#pragma unroll
        for (int j = 0; j < 4; ++j)
            bf[j] = *(const half8*)&Bs[(wn + j * 16 + lm) * 32 + quad * 8];
#pragma unroll
        for (int i = 0; i < 4; ++i)
#pragma unroll
            for (int j = 0; j < 4; ++j)
                acc[i][j] = __builtin_amdgcn_mfma_f32_16x16x32_f16(af[i], bf[j], acc[i][j], 0, 0, 0);
    }

#pragma unroll
    for (int i = 0; i < 4; ++i)
#pragma unroll
        for (int r = 0; r < 4; ++r) {
            int row = m0 + wm + i * 16 + quad * 4 + r;
            float dd = dinv[row];  // 0 on pad rows
#pragma unroll
            for (int j = 0; j < 4; ++j) {
                int col = n0 + wn + j * 16 + lm;
                G[(size_t)row * DIM + col] = (_Float16)(dd * acc[i][j][r]);
            }
        }
}

// ---------------------------------------------------------------- MFMA GEMM (fp32 A, pipelined)
// Layer 1: reads features fp32 directly; A-prefetch into registers is placed
// textually after the MFMA stage so the loads overlap compute; the cvt+ds_write
// happens at the next loop top from registers. Rows >= N_NODES staged as zero.
__global__ __launch_bounds__(256) void k_gemm_f32A(const float* __restrict__ A,
                                                   const _Float16* __restrict__ Bt,
                                                   const float* __restrict__ dinv,
                                                   _Float16* __restrict__ G) {
    __shared__ _Float16 As[128 * 32];  // [m][k], k contiguous
    __shared__ _Float16 Bs[128 * 32];  // [n][k], k contiguous

    int t = threadIdx.x;
    int w = t >> 6, lane = t & 63;
    int lm = lane & 15, quad = lane >> 4;
    int m0 = blockIdx.x * 128, n0 = blockIdx.y * 128;
    int wm = (w & 1) * 64, wn = (w >> 1) * 64;

    // this thread's two A segments (fixed across k-iterations)
    int s0 = t, s1 = 256 + t;
    int am0 = s0 >> 2, ak0 = (s0 & 3) * 8;
    int am1 = s1 >> 2, ak1 = (s1 & 3) * 8;
    bool v0 = (m0 + am0) < N_NODES;
    bool v1 = (m0 + am1) < N_NODES;
    const float* ap0 = A + (size_t)(m0 + am0) * DIM + ak0;
    const float* ap1 = A + (size_t)(m0 + am1) * DIM + ak1;

    floatx4 acc[4][4];
#pragma unroll
    for (int i = 0; i < 4; ++i)
#pragma unroll
        for (int j = 0; j < 4; ++j) acc[i][j] = (floatx4){0.f, 0.f, 0.f, 0.f};

    float4 z4 = make_float4(0.f, 0.f, 0.f, 0.f);
    float4 p0a = z4, p0b = z4, p1a = z4, p1b = z4;
    if (v0) { p0a = *(const float4*)(ap0); p0b = *(const float4*)(ap0 + 4); }
    if (v1) { p1a = *(const float4*)(ap1); p1b = *(const float4*)(ap1 + 4); }

    for (int k0 = 0; k0 < DIM; k0 += 32) {
        __syncthreads();  // prior-iteration LDS reads complete
#pragma unroll
        for (int i = 0; i < 2; ++i) {  // B: async direct-to-LDS
            int s = i * 256 + t;
            int m = s >> 2, kk = (s & 3) * 8;
            GLD16(Bt + (size_t)(n0 + m) * DIM + k0 + kk, Bs + s * 8);
        }
        {  // A: cvt prefetched regs -> LDS
            half8 h0, h1;
            h0[0] = (_Float16)p0a.x; h0[1] = (_Float16)p0a.y;
            h0[2] = (_Float16)p0a.z; h0[3] = (_Float16)p0a.w;
            h0[4] = (_Float16)p0b.x; h0[5] = (_Float16)p0b.y;
            h0[6] = (_Float16)p0b.z; h0[7] = (_Float16)p0b.w;
            h1[0] = (_Float16)p1a.x; h1[1] = (_Float16)p1a.y;
            h1[2] = (_Float16)p1a.z; h1[3] = (_Float16)p1a.w;
            h1[4] = (_Float16)p1b.x; h1[5] = (_Float16)p1b.y;
            h1[6] = (_Float16)p1b.z; h1[7] = (_Float16)p1b.w;
            *(half8*)&As[s0 * 8] = h0;
            *(half8*)&As[s1 * 8] = h1;
        }
        __syncthreads();  // staging drained

        half8 af[4], bf[4];
#pragma unroll
        for (int i = 0; i < 4; ++i)
            af[i] = *(const half8*)&As[(wm + i * 16 + lm) * 32 + quad * 8];
#pragma unroll
        for (int j = 0; j < 4; ++j)
            bf[j] = *(const half8*)&Bs[(wn + j * 16 + lm) * 32 + quad * 8];
#pragma unroll
        for (int i = 0; i < 4; ++i)
#pragma unroll
            for (int j = 0; j < 4; ++j)
                acc[i][j] = __builtin_amdgcn_mfma_f32_16x16x32_f16(af[i], bf[j], acc[i][j], 0, 0, 0);

        // prefetch next k-tile's A (overlaps the MFMA stage; drained at next top barrier)
        int kn = k0 + 32;
        if (kn < DIM) {
            if (v0) { p0a = *(const float4*)(ap0 + kn); p0b = *(const float4*)(ap0 + kn + 4); }
            if (v1) { p1a = *(const float4*)(ap1 + kn); p1b = *(const float4*)(ap1 + kn + 4); }
        }
    }

#pragma unroll
    for (int i = 0; i < 4; ++i)
#pragma unroll
        for (int r = 0; r < 4; ++r) {
            int row = m0 + wm + i * 16 + quad * 4 + r;
            float dd = dinv[row];  // 0 on pad rows
#pragma unroll
            for (int j = 0; j < 4; ++j) {
                int col = n0 + wn + j * 16 + lm;
                G[(size_t)row * DIM + col] = (_Float16)(dd * acc[i][j][r]);
            }
        }
}

// ---------------------------------------------------------------- agg layer 1 (f16 out)
// XCD-affine feature-chunked gather + serial per-node edge loops (degree-sorted).
// Accumulation via v_dot2_f32_f16 (f32 accumulate): halves VALU vs cvt+add.
__global__ __launch_bounds__(256) void k_agg1(const _Float16* __restrict__ g,
                                              const float* __restrict__ dinv,
                                              const int* __restrict__ offs,
                                              const int* __restrict__ csr_src,
                                              const int* __restrict__ sorted,
                                              const float* __restrict__ bias,
                                              _Float16* __restrict__ out) {
    int chunk = blockIdx.x & 7;
    int grp = blockIdx.x >> 3;
    int w = threadIdx.x >> 6, lane = threadIdx.x & 63;
    int slot = lane >> 3, fg = lane & 7;
    int idx = grp * 32 + w * 8 + slot;         // 0..MP-1 exactly (628*32 = 20096)
    int node = sorted[idx];
    if ((unsigned)node >= (unsigned)MP) return;  // defensive: never scribble OOB
    int fbase = chunk * 64 + fg * 8;
    size_t obase = (size_t)node * DIM + fbase;

    if (node >= N_NODES) {  // pad row: zero this 16B (x1f feeds GEMM2's A)
        half8 z;
#pragma unroll
        for (int i = 0; i < 8; ++i) z[i] = (_Float16)0.f;
        *(half8*)&out[obase] = z;
        return;
    }

    float acc[8];
    half8 self = *(const half8*)&g[obase];
#pragma unroll
    for (int i = 0; i < 8; ++i) acc[i] = (float)self[i];

    int beg = offs[node], end = offs[node + 1];
    int e = beg;
    for (; e + 8 <= end; e += 8) {
        int s0 = csr_src[e],     s1 = csr_src[e + 1], s2 = csr_src[e + 2], s3 = csr_src[e + 3];
        int s4 = csr_src[e + 4], s5 = csr_src[e + 5], s6 = csr_src[e + 6], s7 = csr_src[e + 7];
        half8 v0 = *(const half8*)&g[(size_t)s0 * DIM + fbase];
        half8 v1 = *(const half8*)&g[(size_t)s1 * DIM + fbase];
        half8 v2 = *(const half8*)&g[(size_t)s2 * DIM + fbase];
        half8 v3 = *(const half8*)&g[(size_t)s3 * DIM + fbase];
        half8 v4 = *(const half8*)&g[(size_t)s4 * DIM + fbase];
        half8 v5 = *(const half8*)&g[(size_t)s5 * DIM + fbase];
        half8 v6 = *(const half8*)&g[(size_t)s6 * DIM + fbase];
        half8 v7 = *(const half8*)&g[(size_t)s7 * DIM + fbase];
#pragma unroll
        for (int i = 0; i < 8; ++i) {
            acc[i] = dot2sum(v0[i], v1[i], acc[i]);
            acc[i] = dot2sum(v2[i], v3[i], acc[i]);
            acc[i] = dot2sum(v4[i], v5[i], acc[i]);
            acc[i] = dot2sum(v6[i], v7[i], acc[i]);
        }
    }
    for (; e + 4 <= end; e += 4) {
        int s0 = csr_src[e], s1 = csr_src[e + 1], s2 = csr_src[e + 2], s3 = csr_src[e + 3];
        half8 v0 = *(const half8*)&g[(size_t)s0 * DIM + fbase];
        half8 v1 = *(const half8*)&g[(size_t)s1 * DIM + fbase];
        half8 v2 = *(const half8*)&g[(size_t)s2 * DIM + fbase];
        half8 v3 = *(const half8*)&g[(size_t)s3 * DIM + fbase];
#pragma unroll
        for (int i = 0; i < 8; ++i) {
            acc[i] = dot2sum(v0[i], v1[i], acc[i]);
            acc[i] = dot2sum(v2[i], v3[i], acc[i]);
        }
    }
    for (; e < end; ++e) {
        int s = csr_src[e];
        half8 v = *(const half8*)&g[(size_t)s * DIM + fbase];
#pragma unroll
        for (int i = 0; i < 8; ++i) acc[i] += (float)v[i];
    }

    float dd = dinv[node];
    float4 b0 = *(const float4*)&bias[fbase];
    float4 b1 = *(const float4*)&bias[fbase + 4];
    float bb[8] = {b0.x, b0.y, b0.z, b0.w, b1.x, b1.y, b1.z, b1.w};
    half8 o;
#pragma unroll
    for (int i = 0; i < 8; ++i) o[i] = (_Float16)fmaxf(fmaf(dd, acc[i], bb[i]), 0.f);
    *(half8*)&out[obase] = o;
}

// ---------------------------------------------------------------- agg layer 2 + fused max-pool
// Per-node result never hits memory: block-level LDS max-reduction over the 32
// nodes, one atomicMax per feature per block into d_out. Pool on fp32 values
// (replay-stable). No early returns — every thread reaches the barrier.
__global__ __launch_bounds__(256) void k_agg_pool(const _Float16* __restrict__ g,
                                                  const float* __restrict__ dinv,
                                                  const int* __restrict__ offs,
                                                  const int* __restrict__ csr_src,
                                                  const int* __restrict__ sorted,
                                                  const float* __restrict__ bias,
                                                  float* __restrict__ out) {
    __shared__ float lmax[32 * 68];  // 32 node-rows x 64 feats, stride 68 (2-way banks = free)
    int chunk = blockIdx.x & 7;
    int grp = blockIdx.x >> 3;
    int w = threadIdx.x >> 6, lane = threadIdx.x & 63;
    int slot = lane >> 3, fg = lane & 7;
    int idx = grp * 32 + w * 8 + slot;
    int node = sorted[idx];
    int fbase = chunk * 64 + fg * 8;
    bool valid = ((unsigned)node < (unsigned)N_NODES);

    float o[8];
#pragma unroll
    for (int i = 0; i < 8; ++i) o[i] = 0.f;

    if (valid) {
        size_t obase = (size_t)node * DIM + fbase;
        float acc[8];
        half8 self = *(const half8*)&g[obase];
#pragma unroll
        for (int i = 0; i < 8; ++i) acc[i] = (float)self[i];

        int beg = offs[node], end = offs[node + 1];
        int e = beg;
        for (; e + 8 <= end; e += 8) {
            int s0 = csr_src[e],     s1 = csr_src[e + 1], s2 = csr_src[e + 2], s3 = csr_src[e + 3];
            int s4 = csr_src[e + 4], s5 = csr_src[e + 5], s6 = csr_src[e + 6], s7 = csr_src[e + 7];
            half8 v0 = *(const half8*)&g[(size_t)s0 * DIM + fbase];
            half8 v1 = *(const half8*)&g[(size_t)s1 * DIM + fbase];
            half8 v2 = *(const half8*)&g[(size_t)s2 * DIM + fbase];
            half8 v3 = *(const half8*)&g[(size_t)s3 * DIM + fbase];
            half8 v4 = *(const half8*)&g[(size_t)s4 * DIM + fbase];
            half8 v5 = *(const half8*)&g[(size_t)s5 * DIM + fbase];
            half8 v6 = *(const half8*)&g[(size_t)s6 * DIM + fbase];
            half8 v7 = *(const half8*)&g[(size_t)s7 * DIM + fbase];
#pragma unroll
            for (int i = 0; i < 8; ++i) {
                acc[i] = dot2sum(v0[i], v1[i], acc[i]);
                acc[i] = dot2sum(v2[i], v3[i], acc[i]);
                acc[i] = dot2sum(v4[i], v5[i], acc[i]);
                acc[i] = dot2sum(v6[i], v7[i], acc[i]);
            }
        }
        for (; e + 4 <= end; e += 4) {
            int s0 = csr_src[e], s1 = csr_src[e + 1], s2 = csr_src[e + 2], s3 = csr_src[e + 3];
            half8 v0 = *(const half8*)&g[(size_t)s0 * DIM + fbase];
            half8 v1 = *(const half8*)&g[(size_t)s1 * DIM + fbase];
            half8 v2 = *(const half8*)&g[(size_t)s2 * DIM + fbase];
            half8 v3 = *(const half8*)&g[(size_t)s3 * DIM + fbase];
#pragma unroll
            for (int i = 0; i < 8; ++i) {
                acc[i] = dot2sum(v0[i], v1[i], acc[i]);
                acc[i] = dot2sum(v2[i], v3[i], acc[i]);
            }
        }
        for (; e < end; ++e) {
            int s = csr_src[e];
            half8 v = *(const half8*)&g[(size_t)s * DIM + fbase];
#pragma unroll
            for (int i = 0; i < 8; ++i) acc[i] += (float)v[i];
        }

        float dd = dinv[node];
        float4 b0 = *(const float4*)&bias[fbase];
        float4 b1 = *(const float4*)&bias[fbase + 4];
        float bb[8] = {b0.x, b0.y, b0.z, b0.w, b1.x, b1.y, b1.z, b1.w};
#pragma unroll
        for (int i = 0; i < 8; ++i) o[i] = fmaxf(fmaf(dd, acc[i], bb[i]), 0.f);
    }

    // block max-reduce over 32 nodes
    int row = w * 8 + slot;
#pragma unroll
    for (int i = 0; i < 8; ++i) lmax[row * 68 + fg * 8 + i] = o[i];
    __syncthreads();
    if (threadIdx.x < 64) {
        int c = threadIdx.x;
        float m = 0.f;
#pragma unroll
        for (int r = 0; r < 32; ++r) m = fmaxf(m, lmax[r * 68 + c]);
        atomicMax((int*)&out[chunk * 64 + c], __float_as_int(m));  // post-ReLU >= 0
    }
}

// ---------------------------------------------------------------- launch
extern "C" void kernel_launch(void* const* d_in, const int* in_sizes, int n_in,
                              void* d_out, int out_size, void* d_ws, size_t ws_size,
                              hipStream_t stream) {
    const float* features = (const float*)d_in[0];
    const int*   ei       = (const int*)d_in[1];
    const float* W1       = (const float*)d_in[3];
    const float* b1       = (const float*)d_in[4];
    const float* W2       = (const float*)d_in[5];
    const float* b2       = (const float*)d_in[6];
    float* out = (float*)d_out;

    const int* src = ei;
    const int* dst = ei + N_EDGES;

    char* p = (char*)d_ws;
    auto alloc = [&](size_t bytes) { void* r = p; p += (bytes + 255) & ~(size_t)255; return r; };
    // zero-region: cnt + hist + bincur (single memset)
    int*      cnt    = (int*)alloc(N_NODES * 4);
    int*      hist   = (int*)alloc(NBIN * 4);
    int*      bincur = (int*)alloc(NBIN * 4);
    char*     zeroEnd = p;
    int*      offs   = (int*)alloc((N_NODES + 1) * 4);
    int*      cursor = (int*)alloc(N_NODES * 4);
    float*    dinv   = (float*)alloc(MP * 4);
    int*      csr    = (int*)alloc(N_EDGES * 4);
    int*      bsum   = (int*)alloc(SCAN_BLOCKS * 4);
    int*      sorted = (int*)alloc(MP * 4);
    _Float16* Wt1  = (_Float16*)alloc((size_t)DIM * DIM * 2);
    _Float16* Wt2  = (_Float16*)alloc((size_t)DIM * DIM * 2);
    _Float16* gbuf = (_Float16*)alloc((size_t)MP * DIM * 2);
    _Float16* x1f  = (_Float16*)alloc((size_t)MP * DIM * 2);

    // --- zero cnt/hist/bincur + out
    hipMemsetAsync(cnt, 0, (size_t)(zeroEnd - (char*)cnt), stream);
    hipMemsetAsync(out, 0, DIM * 4, stream);

    // --- graph norm + CSR build (scan_b folded into scan_c)
    k_count<<<FILL_BLOCKS, 256, 0, stream>>>(dst, cnt);
    k_scan_a<<<SCAN_BLOCKS, 256, 0, stream>>>(cnt, bsum);
    k_scan_c<<<SCAN_BLOCKS, 256, 0, stream>>>(cnt, bsum, offs, cursor, dinv, hist);

    // --- fused: CSR fill + W transposes + degree sort
    k_prep<<<FILL_BLOCKS + W_BLOCKS + SORT_BLOCKS, 256, 0, stream>>>(
        src, dst, cursor, csr, W1, W2, Wt1, Wt2, cnt, hist, bincur, sorted);

    dim3 ggrd(MP / 128, DIM / 128);

    // --- layer 1 (A = fp32 features, pipelined staging; f16 out)
    k_gemm_f32A<<<ggrd, 256, 0, stream>>>(features, Wt1, dinv, gbuf);
    k_agg1<<<8 * (MP / 32), 256, 0, stream>>>(gbuf, dinv, offs, csr, sorted, b1, x1f);

    // --- layer 2 (A = f16 x1f) + fused fp32 max-pool into d_out
    k_gemm_f16<<<ggrd, 256, 0, stream>>>(x1f, Wt2, dinv, gbuf);
    k_agg_pool<<<8 * (MP / 32), 256, 0, stream>>>(gbuf, dinv, offs, csr, sorted, b2, out);
}